// Round 10
// baseline (190.111 us; speedup 1.0000x reference)
//
#include <hip/hip_runtime.h>
#include <hip/hip_fp16.h>

// Problem constants
#define S_LEN 128
#define DLOG  128
#define DMEM  16
#define SO    120
#define HDIM  256

typedef _Float16 v8h __attribute__((ext_vector_type(8)));
typedef __fp16 v2hf __attribute__((ext_vector_type(2)));
typedef float v4f __attribute__((ext_vector_type(4)));

union PkU { v2hf h; unsigned u; };
union V8U { v8h v; int u[4]; };

__device__ __forceinline__ v8h splat8(float x) {
  _Float16 h = (_Float16)x;
  v8h v = {h, h, h, h, h, h, h, h};
  return v;
}

// ---------------------------------------------------------------------------
// K1: Q = x@Wq^T + bq,  K = x@Wk^T + bk,  u = x@W1^T
// Half-wave per output row, float4 weight reads, shfl tree reduce.
// ---------------------------------------------------------------------------
__global__ __launch_bounds__(512) void qku_kernel(
    const float* __restrict__ xl, const float* __restrict__ Wq,
    const float* __restrict__ bq, const float* __restrict__ Wk,
    const float* __restrict__ bk, const float* __restrict__ W1,
    float* __restrict__ Q, float* __restrict__ K, float* __restrict__ u) {
  int bj = blockIdx.x, t = threadIdx.x;
  int lane = t & 63, wu = t >> 6;
  int half = lane >> 5, l5 = lane & 31;
  float4 xv = *(const float4*)(xl + bj * 128 + 4 * l5);
  int seg = wu >> 1;  // 0:Q(waves0-1) 1:K(waves2-3) >=2:u(waves4-7)
  const float* wb;
  if (seg == 0) wb = Wq;
  else if (seg == 1) wb = Wk - 128 * 128;
  else wb = W1 - 256 * 128;
  #pragma unroll 4
  for (int step = 0; step < 32; ++step) {
    int ro = wu * 64 + 2 * step + half;
    float4 wv = *(const float4*)(wb + ro * 128 + 4 * l5);
    float v = fmaf(wv.x, xv.x, fmaf(wv.y, xv.y, fmaf(wv.z, xv.z, wv.w * xv.w)));
    v += __shfl_xor(v, 1, 64);
    v += __shfl_xor(v, 2, 64);
    v += __shfl_xor(v, 4, 64);
    v += __shfl_xor(v, 8, 64);
    v += __shfl_xor(v, 16, 64);
    if (l5 == 0) {
      if (seg == 0) Q[bj * 128 + ro] = v + bq[ro];
      else if (seg == 1) K[bj * 128 + (ro - 128)] = v + bk[ro - 128];
      else u[bj * 256 + (ro - 256)] = v;
    }
  }
}

// ---------------------------------------------------------------------------
// K2: attn[b,j,i] = softmax_i( Q[b,j].K[b,i] / sqrt(128) ), 2 bj per block.
// ---------------------------------------------------------------------------
__global__ __launch_bounds__(256) void attn_kernel(
    const float* __restrict__ Q, const float* __restrict__ K,
    float* __restrict__ attn) {
  int t = threadIdx.x;
  int sub = t >> 7, t128 = t & 127;
  int bj = blockIdx.x * 2 + sub, b = bj >> 7;
  int lane = t & 63, wu = (t >> 6) & 1;
  int half = lane >> 5, l5 = lane & 31;
  __shared__ float sc[2][128];
  __shared__ float red[2][128];
  float4 qv = *(const float4*)(Q + bj * 128 + 4 * l5);
  #pragma unroll 4
  for (int step = 0; step < 32; ++step) {
    int ro = wu * 64 + 2 * step + half;
    float4 kv = *(const float4*)(K + (size_t)(b * 128 + ro) * 128 + 4 * l5);
    float v = fmaf(kv.x, qv.x, fmaf(kv.y, qv.y, fmaf(kv.z, qv.z, kv.w * qv.w)));
    v += __shfl_xor(v, 1, 64);
    v += __shfl_xor(v, 2, 64);
    v += __shfl_xor(v, 4, 64);
    v += __shfl_xor(v, 8, 64);
    v += __shfl_xor(v, 16, 64);
    if (l5 == 0) sc[sub][ro] = v * 0.08838834764831845f;  // 1/sqrt(128)
  }
  __syncthreads();
  int i = t128;
  float s = sc[sub][i];
  red[sub][i] = s;
  __syncthreads();
  for (int off = 64; off; off >>= 1) {
    if (i < off) red[sub][i] = fmaxf(red[sub][i], red[sub][i + off]);
    __syncthreads();
  }
  float m = red[sub][0];
  __syncthreads();
  float e = expf(s - m);
  red[sub][i] = e;
  __syncthreads();
  for (int off = 64; off; off >>= 1) {
    if (i < off) red[sub][i] += red[sub][i + off];
    __syncthreads();
  }
  attn[(size_t)bj * 128 + i] = e / red[sub][0];
}

// ---------------------------------------------------------------------------
// K3 (fused h+lie, register-resident h): one bj per block, 128 pairs,
// 8 waves.  A-operand fragments computed IN-REGISTER from u:
//   h[i][k] = tanh((u[bj][k]+b1[k]) - u[b,i][k])
// (u_j + b1 staged once in LDS; u_i rows read from L2).  h never touches
// HBM or LDS.  W2 staged f32->f16 vectorized per K-half.  Epilogue builds
// the full 16x16 f16 skew A per pair in LDS and writes it coalesced to
// slot f16 units [256,512).
// ---------------------------------------------------------------------------
__global__ __launch_bounds__(512) void lie_kernel(
    const float* __restrict__ W2g, const float* __restrict__ b2g,
    const float* __restrict__ ug, const float* __restrict__ b1g,
    float* __restrict__ Tg) {
  __shared__ _Float16 w2t[128 * 136];  // 34816 f16; reused as A-stage (16384)
  __shared__ float ujb[256];           // u[bj] + b1
  int t = threadIdx.x, lane = t & 63;
  int wu = __builtin_amdgcn_readfirstlane(t >> 6);
  int bj = blockIdx.x;  // one bj per block
  int b = bj >> 7;
  int nn = lane & 15, q = lane >> 4;
  int irow = wu * 16 + nn;  // pair's i index (0..127)

  if (t < 256) ujb[t] = ug[bj * 256 + t] + b1g[t];
  // zero pad rows 120..127 once (never overwritten by staging)
  for (int idx = t; idx < 1088; idx += 512) w2t[16320 + idx] = (_Float16)0.f;

  v4f acc[8];
  #pragma unroll
  for (int tt = 0; tt < 8; ++tt) acc[tt] = (v4f){0.f, 0.f, 0.f, 0.f};

  const float* uib = ug + (size_t)(b * 128 + irow) * 256;

  for (int khalf = 0; khalf < 2; ++khalf) {
    __syncthreads();
    // stage W2 K-half: 120 rows x 128 cols, f32->f16 vectorized (float4 in,
    // 2x cvt_pkrtz, 8B out).  3840 float4 units.
    for (int idx = t; idx < 3840; idx += 512) {
      int row = idx >> 5, c4 = (idx & 31) * 4;
      float4 v = *(const float4*)(W2g + row * 256 + khalf * 128 + c4);
      PkU a, b2;
      a.h = __builtin_amdgcn_cvt_pkrtz(v.x, v.y);
      b2.h = __builtin_amdgcn_cvt_pkrtz(v.z, v.w);
      uint2 pk = {a.u, b2.u};
      *(uint2*)(w2t + row * 136 + c4) = pk;
    }
    __syncthreads();
    #pragma unroll
    for (int ks = 0; ks < 4; ++ks) {
      int k0 = khalf * 128 + ks * 32 + 8 * q;
      float4 ui0 = *(const float4*)(uib + k0);
      float4 ui1 = *(const float4*)(uib + k0 + 4);
      float4 uj0 = *(const float4*)(ujb + k0);
      float4 uj1 = *(const float4*)(ujb + k0 + 4);
      float xv[8] = {uj0.x - ui0.x, uj0.y - ui0.y, uj0.z - ui0.z,
                     uj0.w - ui0.w, uj1.x - ui1.x, uj1.y - ui1.y,
                     uj1.z - ui1.z, uj1.w - ui1.w};
      float rv[8];
      #pragma unroll
      for (int k = 0; k < 8; ++k) {
        float x = xv[k];
        float ax = fabsf(x);
        float e = __expf(-2.f * ax);
        float r = __fdividef(1.f - e, 1.f + e);
        rv[k] = copysignf(r, x);
      }
      V8U ah;
      #pragma unroll
      for (int k = 0; k < 4; ++k) {
        PkU pu;
        pu.h = __builtin_amdgcn_cvt_pkrtz(rv[2 * k], rv[2 * k + 1]);
        ah.u[k] = (int)pu.u;
      }
      #pragma unroll
      for (int tt = 0; tt < 8; ++tt) {
        const v8h bf = *(const v8h*)(w2t + (16 * tt + nn) * 136 + ks * 32 + 8 * q);
        acc[tt] = __builtin_amdgcn_mfma_f32_16x16x32_f16(ah.v, bf, acc[tt], 0, 0, 0);
      }
    }
  }

  // precompute per-tt (r,c) positions and bias
  int rc0[8], rc1[8];
  float bbv[8];
  bool val[8];
  #pragma unroll
  for (int tt = 0; tt < 8; ++tt) {
    int n16 = 16 * tt + nn;
    val[tt] = (n16 < 120);
    // closed-form inverse of triangular index: r = floor((31-sqrt(961-8n))/2)
    float fr_ = floorf((31.0f - sqrtf(961.0f - 8.0f * (float)n16)) * 0.5f);
    int r = (int)fr_;
    int Sr = 15 * r - ((r * (r - 1)) >> 1);
    int c = n16 - Sr + r + 1;
    rc0[tt] = r * 16 + c;
    rc1[tt] = c * 16 + r;
    bbv[tt] = val[tt] ? b2g[n16] : 0.f;
  }

  _Float16* hw = (_Float16*)Tg;
  _Float16* aSt = w2t;  // [64 local pairs][256] f16 = 16384 f16 per pass
  for (int pass = 0; pass < 2; ++pass) {
    __syncthreads();
    // scatter phase: lanes owning pairs in this pass write A to LDS
    #pragma unroll
    for (int reg = 0; reg < 4; ++reg) {
      int pidx = 4 * q + reg;
      if ((pidx >> 3) == pass) {
        _Float16* ab = aSt + (wu * 8 + (pidx & 7)) * 256;
        #pragma unroll
        for (int tt = 0; tt < 8; ++tt) {
          if (val[tt]) {
            _Float16 hv = (_Float16)(acc[tt][reg] + bbv[tt]);
            ab[rc0[tt]] = hv;
            ab[rc1[tt]] = -hv;
          }
        }
        ab[nn * 17] = (_Float16)0.f;  // diag (each nn-lane writes one)
      }
    }
    __syncthreads();
    // copy phase: 2048 v8h units, fully coalesced
    #pragma unroll
    for (int k = 0; k < 4; ++k) {
      int unit = t + k * 512;
      int lp = unit >> 5, off = (unit & 31) * 8;
      int g = bj * 128 + (lp >> 3) * 16 + pass * 8 + (lp & 7);
      *(v8h*)(hw + (size_t)g * 512 + 256 + off) = *(const v8h*)(aSt + lp * 256 + off);
    }
  }
}

// ---------------------------------------------------------------------------
// K4: per-pair T = expm(skew(lie)) via Paterson-Stockmeyer even/odd split:
//   exp(A) = C(B) + A*Q(B),  B = A^2 (SYMMETRIC -> one bpermute transform
//   serves as BOTH MFMA operands).
// 4 pairs per wave (4 independent dependency chains).
// Scaling bound: ||A||_2 <= ||A||_F / sqrt(2) (skew eigenvalue pairing);
// s extracted from the float exponent bits (no serial loop).
// Epilogue computes attn-weighted transported partials (per-block) to `part`.
// ---------------------------------------------------------------------------
__device__ __forceinline__ void split8(const float* x, v8h& hi, v8h& lo) {
  union U { v8h v; v2hf p[4]; } H, L;
  #pragma unroll
  for (int i = 0; i < 4; ++i) {
    float a = x[2 * i], b = x[2 * i + 1];
    v2hf h = __builtin_amdgcn_cvt_pkrtz(a, b);
    float ra = (float)h[0], rb = (float)h[1];
    v2hf l = __builtin_amdgcn_cvt_pkrtz(a - ra, b - rb);
    H.p[i] = h;
    L.p[i] = l;
  }
  hi = H.v;
  lo = L.v;
}

__global__ __launch_bounds__(256) void expm_kernel(
    float* __restrict__ Tg, const float* __restrict__ attn,
    const float* __restrict__ xm, float* __restrict__ part) {
  __shared__ float ErB_all[4][1280];  // per-wave [4 pairs][320] f32
  __shared__ float sred[4][16];
  int t = threadIdx.x, lane = t & 63;
  int wu = __builtin_amdgcn_readfirstlane(t >> 6);
  int pbase = blockIdx.x * 16 + wu * 4;
  int nn = lane & 15, q = lane >> 4, b8 = (q & 1) * 8;
  float* ErW = ErB_all[wu];
  const _Float16* hf = (const _Float16*)Tg;

  int idxA = ((2 * (q & 1)) * 16 + nn) * 4;
  int idxB = idxA + 64;

  // ---- load A rows (full skew f16), norm -> scaling, frags ----
  float scv[4];
  int sv[4];
  V8U Apk[4];
  v4f Af[4];
  #pragma unroll
  for (int j = 0; j < 4; ++j) {
    size_t p = (size_t)(pbase + j);
    const _Float16* Ap = hf + p * 512 + 256;
    v8h rowh = *(const v8h*)(Ap + nn * 16 + b8);
    float s2 = 0.f;
    #pragma unroll
    for (int k = 0; k < 8; ++k) {
      float xf = (float)rowh[k];
      s2 = fmaf(xf, xf, s2);
    }
    #pragma unroll
    for (int off = 1; off < 64; off <<= 1) s2 += __shfl_xor(s2, off, 64);
    // wave-sum counts every entry twice -> s2 = 2*||A||_F^2;
    // skew: ||A||_2 <= ||A||_F/sqrt(2) = 0.5*sqrt(s2)
    float bound = 0.5f * sqrtf(s2);
    // s = clamp(ceil(log2(bound)), 0, 12) via exponent bits
    int bb = __float_as_int(bound);
    int s = ((bb >> 23) & 255) - 126;
    s = min(max(s, 0), 12);
    sv[j] = __builtin_amdgcn_readfirstlane(s);
    scv[j] = __int_as_float((127 - sv[j]) << 23);  // 2^-s
    v8h sch = splat8(scv[j]);
    V8U ap;
    ap.v = rowh * sch;  // exact: pow2 scale in f16
    #pragma unroll
    for (int i = 0; i < 4; ++i) Apk[j].u[i] = ap.u[i];
    #pragma unroll
    for (int reg = 0; reg < 4; ++reg)
      Af[j][reg] = (float)Ap[(4 * q + reg) * 16 + nn] * scv[j];
  }

  // identity frags in gather layout, pre-scaled by combo coefficients
  V8U IC1, IC2;
  #pragma unroll
  for (int i = 0; i < 4; ++i) {
    float d0 = (b8 + 2 * i == nn) ? 1.f : 0.f;
    float d1 = (b8 + 2 * i + 1 == nn) ? 1.f : 0.f;
    PkU u1, u2;
    u1.h = __builtin_amdgcn_cvt_pkrtz(10.666667f * d0, 10.666667f * d1);   // 256/24
    u2.h = __builtin_amdgcn_cvt_pkrtz(2.1333333f * d0, 2.1333333f * d1);   // 256/120
    IC1.u[i] = (int)u1.u;
    IC2.u[i] = (int)u2.u;
  }
  v8h k1a = splat8(7.9365079e-4f);   // 32/40320
  v8h k1b = splat8(0.17777778f);     // 128/720
  v8h k2a = splat8(8.8183422e-5f);   // 32/362880
  v8h k2b = splat8(2.5396825e-2f);   // 128/5040
  v4f z4 = {0.f, 0.f, 0.f, 0.f};

  // ---- MFMA1: cB = 2*B (B = A^2);  B-frag of A = -A rows (sign-flip) ----
  v4f cB[4];
  #pragma unroll
  for (int j = 0; j < 4; ++j) {
    V8U bfa;
    #pragma unroll
    for (int i = 0; i < 4; ++i) bfa.u[i] = Apk[j].u[i] ^ 0x80008000;
    cB[j] = __builtin_amdgcn_mfma_f32_16x16x32_f16(Apk[j].v, bfa.v, z4, 0, 0, 0);
  }

  // ---- transform 1: fB = gather(2B) ----
  V8U fB[4];
  #pragma unroll
  for (int j = 0; j < 4; ++j) {
    PkU u0, u1;
    u0.h = __builtin_amdgcn_cvt_pkrtz(cB[j][0], cB[j][1]);
    u1.h = __builtin_amdgcn_cvt_pkrtz(cB[j][2], cB[j][3]);
    fB[j].u[0] = __builtin_amdgcn_ds_bpermute(idxA, (int)u0.u);
    fB[j].u[1] = __builtin_amdgcn_ds_bpermute(idxA, (int)u1.u);
    fB[j].u[2] = __builtin_amdgcn_ds_bpermute(idxB, (int)u0.u);
    fB[j].u[3] = __builtin_amdgcn_ds_bpermute(idxB, (int)u1.u);
  }

  // ---- MFMA2 + transform 2: fB2 = gather(8*B^2) ----
  V8U fB2[4];
  #pragma unroll
  for (int j = 0; j < 4; ++j) {
    v4f c = __builtin_amdgcn_mfma_f32_16x16x32_f16(fB[j].v, fB[j].v, z4, 0, 0, 0);
    PkU u0, u1;
    u0.h = __builtin_amdgcn_cvt_pkrtz(c[0], c[1]);
    u1.h = __builtin_amdgcn_cvt_pkrtz(c[2], c[3]);
    fB2[j].u[0] = __builtin_amdgcn_ds_bpermute(idxA, (int)u0.u);
    fB2[j].u[1] = __builtin_amdgcn_ds_bpermute(idxA, (int)u1.u);
    fB2[j].u[2] = __builtin_amdgcn_ds_bpermute(idxB, (int)u0.u);
    fB2[j].u[3] = __builtin_amdgcn_ds_bpermute(idxB, (int)u1.u);
  }

  // ---- fused tail: combos -> MFMA3/4 -> fQ gather -> MFMA5 -> E ----
  v4f E[4];
  #pragma unroll
  for (int j = 0; j < 4; ++j) {
    V8U M1, M2;
    M1.v = fB2[j].v * k1a + (fB[j].v * k1b + IC1.v);
    M2.v = fB2[j].v * k2a + (fB[j].v * k2b + IC2.v);
    v4f c3m = __builtin_amdgcn_mfma_f32_16x16x32_f16(M1.v, fB2[j].v, z4, 0, 0, 0);
    v4f c4m = __builtin_amdgcn_mfma_f32_16x16x32_f16(M2.v, fB2[j].v, z4, 0, 0, 0);
    v4f Cc, Qc;
    #pragma unroll
    for (int reg = 0; reg < 4; ++reg) {
      float dg = (4 * q + reg == nn) ? 1.f : 0.f;
      Cc[reg] = fmaf(c3m[reg], 2.44140625e-4f,
                     fmaf(cB[j][reg], 0.25f, dg + Af[j][reg]));
      Qc[reg] = fmaf(c4m[reg], 2.44140625e-4f, cB[j][reg] * 0.083333333f);
    }
    PkU u0, u1;
    u0.h = __builtin_amdgcn_cvt_pkrtz(Qc[0], Qc[1]);
    u1.h = __builtin_amdgcn_cvt_pkrtz(Qc[2], Qc[3]);
    V8U fQ;
    fQ.u[0] = __builtin_amdgcn_ds_bpermute(idxA, (int)u0.u);
    fQ.u[1] = __builtin_amdgcn_ds_bpermute(idxA, (int)u1.u);
    fQ.u[2] = __builtin_amdgcn_ds_bpermute(idxB, (int)u0.u);
    fQ.u[3] = __builtin_amdgcn_ds_bpermute(idxB, (int)u1.u);
    v4f c5 = __builtin_amdgcn_mfma_f32_16x16x32_f16(Apk[j].v, fQ.v, z4, 0, 0, 0);
    E[j] = Cc + c5 * 0.5f;
  }

  // ---- squarings: E <- E*E (A-side exact hi/lo via LDS row transpose) ----
  int smax = max(max(sv[0], sv[1]), max(sv[2], sv[3]));
  for (int it = 0; it < smax; ++it) {
    #pragma unroll
    for (int j = 0; j < 4; ++j) {
      if (it < sv[j]) {
        float* Erp = ErW + j * 320;
        PkU u0, u1;
        u0.h = __builtin_amdgcn_cvt_pkrtz(E[j][0], E[j][1]);
        u1.h = __builtin_amdgcn_cvt_pkrtz(E[j][2], E[j][3]);
        V8U bfe;
        bfe.u[0] = __builtin_amdgcn_ds_bpermute(idxA, (int)u0.u);
        bfe.u[1] = __builtin_amdgcn_ds_bpermute(idxA, (int)u1.u);
        bfe.u[2] = __builtin_amdgcn_ds_bpermute(idxB, (int)u0.u);
        bfe.u[3] = __builtin_amdgcn_ds_bpermute(idxB, (int)u1.u);
        #pragma unroll
        for (int reg = 0; reg < 4; ++reg)
          Erp[(4 * q + reg) * 20 + nn] = E[j][reg];
        asm volatile("s_waitcnt lgkmcnt(0)" ::: "memory");
        float4 a0 = *(const float4*)(Erp + nn * 20 + b8);
        float4 a1 = *(const float4*)(Erp + nn * 20 + b8 + 4);
        float xa[8] = {a0.x, a0.y, a0.z, a0.w, a1.x, a1.y, a1.z, a1.w};
        v8h ahi, alo;
        split8(xa, ahi, alo);
        v8h Ecat = (q < 2) ? ahi : alo;
        v4f z = {0.f, 0.f, 0.f, 0.f};
        E[j] = __builtin_amdgcn_mfma_f32_16x16x32_f16(Ecat, bfe.v, z, 0, 0, 0);
      }
    }
  }

  // ---- store T + fused attn-weighted transported partials ----
  float pacc[4] = {0.f, 0.f, 0.f, 0.f};
  #pragma unroll
  for (int j = 0; j < 4; ++j) {
    int p = pbase + j;
    float* dst = Tg + (size_t)p * 256;
    #pragma unroll
    for (int reg = 0; reg < 4; ++reg)
      dst[(4 * q + reg) * 16 + nn] = E[j][reg];
    int b = p >> 14, i = p & 127;
    float xv = xm[((b << 7) + i) * 16 + nn];
    float aw = attn[(size_t)p] * xv;
    #pragma unroll
    for (int reg = 0; reg < 4; ++reg)
      pacc[reg] = fmaf(aw, E[j][reg], pacc[reg]);
  }
  #pragma unroll
  for (int reg = 0; reg < 4; ++reg) {
    #pragma unroll
    for (int off = 1; off < 16; off <<= 1)
      pacc[reg] += __shfl_xor(pacc[reg], off, 64);
  }
  if (nn == 0) {
    #pragma unroll
    for (int reg = 0; reg < 4; ++reg) sred[wu][4 * q + reg] = pacc[reg];
  }
  __syncthreads();
  if (t < 16)
    part[(size_t)blockIdx.x * 16 + t] =
        sred[0][t] + sred[1][t] + sred[2][t] + sred[3][t];
}

// ---------------------------------------------------------------------------
// K5: settled[bj] = sum of 8 per-block partials; out = settled @ Wo^T + bo
// ---------------------------------------------------------------------------
__global__ __launch_bounds__(64) void settle_fin_kernel(
    const float* __restrict__ part, const float* __restrict__ Wo,
    const float* __restrict__ bo, float* __restrict__ outp) {
  int bj = blockIdx.x, t = threadIdx.x;
  int r = t & 15, e0 = t >> 4;
  const float* pb = part + (size_t)bj * 128;  // 8 partials of 16
  float s = pb[e0 * 16 + r] + pb[(e0 + 4) * 16 + r];
  __shared__ float sf[64];
  sf[t] = s;
  __syncthreads();
  if (t < 16) sf[t] = sf[t] + sf[16 + t] + sf[32 + t] + sf[48 + t];
  __syncthreads();
  if (t < 16) {
    float o = bo[t];
    const float* wr = Wo + t * 16;
    #pragma unroll
    for (int c = 0; c < 16; ++c) o = fmaf(wr[c], sf[c], o);
    outp[bj * 16 + t] = o;
  }
}

// ---------------------------------------------------------------------------
extern "C" void kernel_launch(void* const* d_in, const int* in_sizes, int n_in,
                              void* d_out, int out_size, void* d_ws,
                              size_t ws_size, hipStream_t stream) {
  const float* xl = (const float*)d_in[0];
  const float* xm = (const float*)d_in[1];
  const float* Wq = (const float*)d_in[2];
  const float* bq = (const float*)d_in[3];
  const float* Wk = (const float*)d_in[4];
  const float* bk = (const float*)d_in[5];
  const float* W1 = (const float*)d_in[6];
  const float* b1 = (const float*)d_in[7];
  const float* W2 = (const float*)d_in[8];
  const float* b2 = (const float*)d_in[9];
  const float* Wo = (const float*)d_in[10];
  const float* bo = (const float*)d_in[11];
  float* outp = (float*)d_out;
  float* Tg = outp + 8192;  // [65536][256]: skew A f16 units [256,512) per
                            // slot, then overwritten with T fp32 (h never
                            // touches HBM)
  float* wsf = (float*)d_ws;
  float* Q = wsf;                // 65536
  float* K = wsf + 65536;        // 65536
  float* attn = wsf + 131072;    // 65536
  // u / part alias (stream-serial): u written disp 1, last read disp 3;
  // part first written disp 4.  Footprint stays at the validated 1.25 MB.
  float* u = wsf + 196608;       // 131072
  float* part = wsf + 196608;    // 4096*16 = 65536

  hipLaunchKernelGGL(qku_kernel, dim3(512), dim3(512), 0, stream, xl, Wq, bq, Wk, bk, W1, Q, K, u);
  hipLaunchKernelGGL(attn_kernel, dim3(256), dim3(256), 0, stream, Q, K, attn);
  hipLaunchKernelGGL(lie_kernel, dim3(512), dim3(512), 0, stream, W2, b2, u, b1, Tg);
  hipLaunchKernelGGL(expm_kernel, dim3(4096), dim3(256), 0, stream, Tg, attn, xm, part);
  hipLaunchKernelGGL(settle_fin_kernel, dim3(512), dim3(64), 0, stream, part, Wo, bo, outp);
}

// Round 11
// 187.649 us; speedup vs baseline: 1.0131x; 1.0131x over previous
//
#include <hip/hip_runtime.h>
#include <hip/hip_fp16.h>

// Problem constants
#define S_LEN 128
#define DLOG  128
#define DMEM  16
#define SO    120
#define HDIM  256

typedef _Float16 v8h __attribute__((ext_vector_type(8)));
typedef __fp16 v2hf __attribute__((ext_vector_type(2)));
typedef float v4f __attribute__((ext_vector_type(4)));

union PkU { v2hf h; unsigned u; };
union V8U { v8h v; int u[4]; };

__device__ __forceinline__ v8h splat8(float x) {
  _Float16 h = (_Float16)x;
  v8h v = {h, h, h, h, h, h, h, h};
  return v;
}

// ---------------------------------------------------------------------------
// K1: Q = x@Wq^T + bq,  K = x@Wk^T + bk,  u = x@W1^T
// Half-wave per output row, float4 weight reads, shfl tree reduce.
// Blocks >= 512 (15 of them) do the one-time W2 f32->f16 conversion into the
// dead h sub-windows of Tg (slot s, f16 units [0,256)): W2h[r][c] at
// Tg_f16[r*512 + c].  Disjoint from lie's A windows [256,512); overwritten
// by T (disp 4) after its last read (disp 3).
// ---------------------------------------------------------------------------
__global__ __launch_bounds__(512) void qku_kernel(
    const float* __restrict__ xl, const float* __restrict__ Wq,
    const float* __restrict__ bq, const float* __restrict__ Wk,
    const float* __restrict__ bk, const float* __restrict__ W1,
    const float* __restrict__ W2g, float* __restrict__ Q,
    float* __restrict__ K, float* __restrict__ u, float* __restrict__ Tg) {
  int bj = blockIdx.x, t = threadIdx.x;
  if (bj >= 512) {
    int idx = (bj - 512) * 2048 + t * 4;  // 15*2048 = 30720 = 120*256
    float4 v = *(const float4*)(W2g + idx);
    PkU a, b;
    a.h = __builtin_amdgcn_cvt_pkrtz(v.x, v.y);
    b.h = __builtin_amdgcn_cvt_pkrtz(v.z, v.w);
    uint2 pk = {a.u, b.u};
    _Float16* w2hT = (_Float16*)Tg;
    *(uint2*)(w2hT + (idx >> 8) * 512 + (idx & 255)) = pk;
    return;
  }
  int lane = t & 63, wu = t >> 6;
  int half = lane >> 5, l5 = lane & 31;
  float4 xv = *(const float4*)(xl + bj * 128 + 4 * l5);
  int seg = wu >> 1;  // 0:Q(waves0-1) 1:K(waves2-3) >=2:u(waves4-7)
  const float* wb;
  if (seg == 0) wb = Wq;
  else if (seg == 1) wb = Wk - 128 * 128;
  else wb = W1 - 256 * 128;
  #pragma unroll 4
  for (int step = 0; step < 32; ++step) {
    int ro = wu * 64 + 2 * step + half;
    float4 wv = *(const float4*)(wb + ro * 128 + 4 * l5);
    float v = fmaf(wv.x, xv.x, fmaf(wv.y, xv.y, fmaf(wv.z, xv.z, wv.w * xv.w)));
    v += __shfl_xor(v, 1, 64);
    v += __shfl_xor(v, 2, 64);
    v += __shfl_xor(v, 4, 64);
    v += __shfl_xor(v, 8, 64);
    v += __shfl_xor(v, 16, 64);
    if (l5 == 0) {
      if (seg == 0) Q[bj * 128 + ro] = v + bq[ro];
      else if (seg == 1) K[bj * 128 + (ro - 128)] = v + bk[ro - 128];
      else u[bj * 256 + (ro - 256)] = v;
    }
  }
}

// ---------------------------------------------------------------------------
// K2: attn[b,j,i] = softmax_i( Q[b,j].K[b,i] / sqrt(128) ), 2 bj per block.
// ---------------------------------------------------------------------------
__global__ __launch_bounds__(256) void attn_kernel(
    const float* __restrict__ Q, const float* __restrict__ K,
    float* __restrict__ attn) {
  int t = threadIdx.x;
  int sub = t >> 7, t128 = t & 127;
  int bj = blockIdx.x * 2 + sub, b = bj >> 7;
  int lane = t & 63, wu = (t >> 6) & 1;
  int half = lane >> 5, l5 = lane & 31;
  __shared__ float sc[2][128];
  __shared__ float red[2][128];
  float4 qv = *(const float4*)(Q + bj * 128 + 4 * l5);
  #pragma unroll 4
  for (int step = 0; step < 32; ++step) {
    int ro = wu * 64 + 2 * step + half;
    float4 kv = *(const float4*)(K + (size_t)(b * 128 + ro) * 128 + 4 * l5);
    float v = fmaf(kv.x, qv.x, fmaf(kv.y, qv.y, fmaf(kv.z, qv.z, kv.w * qv.w)));
    v += __shfl_xor(v, 1, 64);
    v += __shfl_xor(v, 2, 64);
    v += __shfl_xor(v, 4, 64);
    v += __shfl_xor(v, 8, 64);
    v += __shfl_xor(v, 16, 64);
    if (l5 == 0) sc[sub][ro] = v * 0.08838834764831845f;  // 1/sqrt(128)
  }
  __syncthreads();
  int i = t128;
  float s = sc[sub][i];
  red[sub][i] = s;
  __syncthreads();
  for (int off = 64; off; off >>= 1) {
    if (i < off) red[sub][i] = fmaxf(red[sub][i], red[sub][i + off]);
    __syncthreads();
  }
  float m = red[sub][0];
  __syncthreads();
  float e = expf(s - m);
  red[sub][i] = e;
  __syncthreads();
  for (int off = 64; off; off >>= 1) {
    if (i < off) red[sub][i] += red[sub][i + off];
    __syncthreads();
  }
  attn[(size_t)bj * 128 + i] = e / red[sub][0];
}

// ---------------------------------------------------------------------------
// K3 (fused h+lie, register-resident h): one bj per block, 128 pairs,
// 8 waves.  A-operand fragments computed IN-REGISTER from u:
//   h[i][k] = tanh((u[bj][k]+b1[k]) - u[b,i][k])
// W2 staged per K-half from the PRE-CONVERTED f16 copy (pure 16B copies).
// Epilogue builds the full 16x16 f16 skew A per pair in LDS and writes it
// coalesced to slot f16 units [256,512).
// ---------------------------------------------------------------------------
__global__ __launch_bounds__(512) void lie_kernel(
    const float* __restrict__ b2g, const float* __restrict__ ug,
    const float* __restrict__ b1g, float* __restrict__ Tg) {
  __shared__ _Float16 w2t[128 * 136];  // 34816 f16; reused as A-stage (16384)
  __shared__ float ujb[256];           // u[bj] + b1
  int t = threadIdx.x, lane = t & 63;
  int wu = __builtin_amdgcn_readfirstlane(t >> 6);
  int bj = blockIdx.x;  // one bj per block
  int b = bj >> 7;
  int nn = lane & 15, q = lane >> 4;
  int irow = wu * 16 + nn;  // pair's i index (0..127)
  const _Float16* w2hT = (const _Float16*)Tg;

  if (t < 256) ujb[t] = ug[bj * 256 + t] + b1g[t];
  // zero pad rows 120..127 once (never overwritten by staging)
  for (int idx = t; idx < 1088; idx += 512) w2t[16320 + idx] = (_Float16)0.f;

  v4f acc[8];
  #pragma unroll
  for (int tt = 0; tt < 8; ++tt) acc[tt] = (v4f){0.f, 0.f, 0.f, 0.f};

  const float* uib = ug + (size_t)(b * 128 + irow) * 256;

  for (int khalf = 0; khalf < 2; ++khalf) {
    __syncthreads();
    // stage W2 K-half: 120 rows x 128 cols f16 = 1920 v8h pure copies
    for (int idx = t; idx < 1920; idx += 512) {
      int row = idx >> 4, cu = (idx & 15) * 8;
      *(v8h*)(w2t + row * 136 + cu) =
          *(const v8h*)(w2hT + row * 512 + khalf * 128 + cu);
    }
    __syncthreads();
    #pragma unroll
    for (int ks = 0; ks < 4; ++ks) {
      int k0 = khalf * 128 + ks * 32 + 8 * q;
      float4 ui0 = *(const float4*)(uib + k0);
      float4 ui1 = *(const float4*)(uib + k0 + 4);
      float4 uj0 = *(const float4*)(ujb + k0);
      float4 uj1 = *(const float4*)(ujb + k0 + 4);
      float xv[8] = {uj0.x - ui0.x, uj0.y - ui0.y, uj0.z - ui0.z,
                     uj0.w - ui0.w, uj1.x - ui1.x, uj1.y - ui1.y,
                     uj1.z - ui1.z, uj1.w - ui1.w};
      float rv[8];
      #pragma unroll
      for (int k = 0; k < 8; ++k) {
        float x = xv[k];
        float ax = fabsf(x);
        float e = __expf(-2.f * ax);
        float r = __fdividef(1.f - e, 1.f + e);
        rv[k] = copysignf(r, x);
      }
      V8U ah;
      #pragma unroll
      for (int k = 0; k < 4; ++k) {
        PkU pu;
        pu.h = __builtin_amdgcn_cvt_pkrtz(rv[2 * k], rv[2 * k + 1]);
        ah.u[k] = (int)pu.u;
      }
      #pragma unroll
      for (int tt = 0; tt < 8; ++tt) {
        const v8h bf = *(const v8h*)(w2t + (16 * tt + nn) * 136 + ks * 32 + 8 * q);
        acc[tt] = __builtin_amdgcn_mfma_f32_16x16x32_f16(ah.v, bf, acc[tt], 0, 0, 0);
      }
    }
  }

  // precompute per-tt (r,c) positions and bias
  int rc0[8], rc1[8];
  float bbv[8];
  bool val[8];
  #pragma unroll
  for (int tt = 0; tt < 8; ++tt) {
    int n16 = 16 * tt + nn;
    val[tt] = (n16 < 120);
    // closed-form inverse of triangular index: r = floor((31-sqrt(961-8n))/2)
    float fr_ = floorf((31.0f - sqrtf(961.0f - 8.0f * (float)n16)) * 0.5f);
    int r = (int)fr_;
    int Sr = 15 * r - ((r * (r - 1)) >> 1);
    int c = n16 - Sr + r + 1;
    rc0[tt] = r * 16 + c;
    rc1[tt] = c * 16 + r;
    bbv[tt] = val[tt] ? b2g[n16] : 0.f;
  }

  _Float16* hw = (_Float16*)Tg;
  _Float16* aSt = w2t;  // [64 local pairs][256] f16 = 16384 f16 per pass
  for (int pass = 0; pass < 2; ++pass) {
    __syncthreads();
    // scatter phase: lanes owning pairs in this pass write A to LDS
    #pragma unroll
    for (int reg = 0; reg < 4; ++reg) {
      int pidx = 4 * q + reg;
      if ((pidx >> 3) == pass) {
        _Float16* ab = aSt + (wu * 8 + (pidx & 7)) * 256;
        #pragma unroll
        for (int tt = 0; tt < 8; ++tt) {
          if (val[tt]) {
            _Float16 hv = (_Float16)(acc[tt][reg] + bbv[tt]);
            ab[rc0[tt]] = hv;
            ab[rc1[tt]] = -hv;
          }
        }
        ab[nn * 17] = (_Float16)0.f;  // diag (each nn-lane writes one)
      }
    }
    __syncthreads();
    // copy phase: 2048 v8h units, fully coalesced
    #pragma unroll
    for (int k = 0; k < 4; ++k) {
      int unit = t + k * 512;
      int lp = unit >> 5, off = (unit & 31) * 8;
      int g = bj * 128 + (lp >> 3) * 16 + pass * 8 + (lp & 7);
      *(v8h*)(hw + (size_t)g * 512 + 256 + off) = *(const v8h*)(aSt + lp * 256 + off);
    }
  }
}

// ---------------------------------------------------------------------------
// K4: per-pair T = expm(skew(lie)) via Paterson-Stockmeyer even/odd split:
//   exp(A) = C(B) + A*Q(B),  B = A^2 (SYMMETRIC -> one bpermute transform
//   serves as BOTH MFMA operands).  4 pairs per wave (4 independent chains).
// Scaling: MFMA1 runs on UNSCALED f16 A (exact inputs, f32 accum); then
// theta^2 <= ||B||_inf (symmetric: row-sum norm bounds spectral norm),
// col-sums nearly free in C-layout; s from exponent bits; cB/Apk/Af scaled
// by exact powers of two afterwards.  Tighter than ||A||_F/sqrt(2) by
// ~0.5 squaring/pair on average.
// Epilogue computes attn-weighted transported partials (per-block) to `part`.
// ---------------------------------------------------------------------------
__device__ __forceinline__ void split8(const float* x, v8h& hi, v8h& lo) {
  union U { v8h v; v2hf p[4]; } H, L;
  #pragma unroll
  for (int i = 0; i < 4; ++i) {
    float a = x[2 * i], b = x[2 * i + 1];
    v2hf h = __builtin_amdgcn_cvt_pkrtz(a, b);
    float ra = (float)h[0], rb = (float)h[1];
    v2hf l = __builtin_amdgcn_cvt_pkrtz(a - ra, b - rb);
    H.p[i] = h;
    L.p[i] = l;
  }
  hi = H.v;
  lo = L.v;
}

__global__ __launch_bounds__(256) void expm_kernel(
    float* __restrict__ Tg, const float* __restrict__ attn,
    const float* __restrict__ xm, float* __restrict__ part) {
  __shared__ float ErB_all[4][1280];  // per-wave [4 pairs][320] f32
  __shared__ float sred[4][16];
  int t = threadIdx.x, lane = t & 63;
  int wu = __builtin_amdgcn_readfirstlane(t >> 6);
  int pbase = blockIdx.x * 16 + wu * 4;
  int nn = lane & 15, q = lane >> 4, b8 = (q & 1) * 8;
  float* ErW = ErB_all[wu];
  const _Float16* hf = (const _Float16*)Tg;

  int idxA = ((2 * (q & 1)) * 16 + nn) * 4;
  int idxB = idxA + 64;

  // ---- load A rows (full skew f16) UNSCALED ----
  V8U Apk[4];
  v4f Af[4];
  #pragma unroll
  for (int j = 0; j < 4; ++j) {
    size_t p = (size_t)(pbase + j);
    const _Float16* Ap = hf + p * 512 + 256;
    v8h rowh = *(const v8h*)(Ap + nn * 16 + b8);
    V8U ap;
    ap.v = rowh;
    #pragma unroll
    for (int i = 0; i < 4; ++i) Apk[j].u[i] = ap.u[i];
    #pragma unroll
    for (int reg = 0; reg < 4; ++reg)
      Af[j][reg] = (float)Ap[(4 * q + reg) * 16 + nn];
  }

  v4f z4 = {0.f, 0.f, 0.f, 0.f};

  // ---- MFMA1 (unscaled): cB_u = 2*A^2 ----
  v4f cB[4];
  #pragma unroll
  for (int j = 0; j < 4; ++j) {
    V8U bfa;
    #pragma unroll
    for (int i = 0; i < 4; ++i) bfa.u[i] = Apk[j].u[i] ^ 0x80008000;
    cB[j] = __builtin_amdgcn_mfma_f32_16x16x32_f16(Apk[j].v, bfa.v, z4, 0, 0, 0);
  }

  // ---- bound from ||B||_inf (col sums of symmetric B), scale exact pow2 ----
  int sv[4];
  #pragma unroll
  for (int j = 0; j < 4; ++j) {
    float cs = fabsf(cB[j][0]) + fabsf(cB[j][1]) + fabsf(cB[j][2]) +
               fabsf(cB[j][3]);
    cs += __shfl_xor(cs, 16, 64);   // sum over q (4 rows-of-4 per column)
    cs += __shfl_xor(cs, 32, 64);
    cs = fmaxf(cs, __shfl_xor(cs, 1, 64));   // max over columns nn
    cs = fmaxf(cs, __shfl_xor(cs, 2, 64));
    cs = fmaxf(cs, __shfl_xor(cs, 4, 64));
    cs = fmaxf(cs, __shfl_xor(cs, 8, 64));
    // cs = ||2B||_inf -> theta^2 <= ||B||_inf = cs/2
    float x = cs * 0.5f;
    int e = ((__float_as_int(x) >> 23) & 255) - 127;  // floor(log2 x)
    int s = min(12, max(0, (e + 2) >> 1));            // >= ceil(0.5*log2 x)
    sv[j] = __builtin_amdgcn_readfirstlane(s);
    float sc = __int_as_float((127 - sv[j]) << 23);   // 2^-s
    float sc2 = sc * sc;                              // 2^-2s
    cB[j] = cB[j] * sc2;
    Apk[j].v = Apk[j].v * splat8(sc);                 // exact pow2 in f16
    Af[j] = Af[j] * sc;
  }

  // identity frags in gather layout, pre-scaled by combo coefficients
  V8U IC1, IC2;
  #pragma unroll
  for (int i = 0; i < 4; ++i) {
    float d0 = (b8 + 2 * i == nn) ? 1.f : 0.f;
    float d1 = (b8 + 2 * i + 1 == nn) ? 1.f : 0.f;
    PkU u1, u2;
    u1.h = __builtin_amdgcn_cvt_pkrtz(10.666667f * d0, 10.666667f * d1);   // 256/24
    u2.h = __builtin_amdgcn_cvt_pkrtz(2.1333333f * d0, 2.1333333f * d1);   // 256/120
    IC1.u[i] = (int)u1.u;
    IC2.u[i] = (int)u2.u;
  }
  v8h k1a = splat8(7.9365079e-4f);   // 32/40320
  v8h k1b = splat8(0.17777778f);     // 128/720
  v8h k2a = splat8(8.8183422e-5f);   // 32/362880
  v8h k2b = splat8(2.5396825e-2f);   // 128/5040

  // ---- transform 1: fB = gather(2B) ----
  V8U fB[4];
  #pragma unroll
  for (int j = 0; j < 4; ++j) {
    PkU u0, u1;
    u0.h = __builtin_amdgcn_cvt_pkrtz(cB[j][0], cB[j][1]);
    u1.h = __builtin_amdgcn_cvt_pkrtz(cB[j][2], cB[j][3]);
    fB[j].u[0] = __builtin_amdgcn_ds_bpermute(idxA, (int)u0.u);
    fB[j].u[1] = __builtin_amdgcn_ds_bpermute(idxA, (int)u1.u);
    fB[j].u[2] = __builtin_amdgcn_ds_bpermute(idxB, (int)u0.u);
    fB[j].u[3] = __builtin_amdgcn_ds_bpermute(idxB, (int)u1.u);
  }

  // ---- MFMA2 + transform 2: fB2 = gather(8*B^2) ----
  V8U fB2[4];
  #pragma unroll
  for (int j = 0; j < 4; ++j) {
    v4f c = __builtin_amdgcn_mfma_f32_16x16x32_f16(fB[j].v, fB[j].v, z4, 0, 0, 0);
    PkU u0, u1;
    u0.h = __builtin_amdgcn_cvt_pkrtz(c[0], c[1]);
    u1.h = __builtin_amdgcn_cvt_pkrtz(c[2], c[3]);
    fB2[j].u[0] = __builtin_amdgcn_ds_bpermute(idxA, (int)u0.u);
    fB2[j].u[1] = __builtin_amdgcn_ds_bpermute(idxA, (int)u1.u);
    fB2[j].u[2] = __builtin_amdgcn_ds_bpermute(idxB, (int)u0.u);
    fB2[j].u[3] = __builtin_amdgcn_ds_bpermute(idxB, (int)u1.u);
  }

  // ---- fused tail: combos -> MFMA3/4 -> fQ gather -> MFMA5 -> E ----
  v4f E[4];
  #pragma unroll
  for (int j = 0; j < 4; ++j) {
    V8U M1, M2;
    M1.v = fB2[j].v * k1a + (fB[j].v * k1b + IC1.v);
    M2.v = fB2[j].v * k2a + (fB[j].v * k2b + IC2.v);
    v4f c3m = __builtin_amdgcn_mfma_f32_16x16x32_f16(M1.v, fB2[j].v, z4, 0, 0, 0);
    v4f c4m = __builtin_amdgcn_mfma_f32_16x16x32_f16(M2.v, fB2[j].v, z4, 0, 0, 0);
    v4f Cc, Qc;
    #pragma unroll
    for (int reg = 0; reg < 4; ++reg) {
      float dg = (4 * q + reg == nn) ? 1.f : 0.f;
      Cc[reg] = fmaf(c3m[reg], 2.44140625e-4f,
                     fmaf(cB[j][reg], 0.25f, dg + Af[j][reg]));
      Qc[reg] = fmaf(c4m[reg], 2.44140625e-4f, cB[j][reg] * 0.083333333f);
    }
    PkU u0, u1;
    u0.h = __builtin_amdgcn_cvt_pkrtz(Qc[0], Qc[1]);
    u1.h = __builtin_amdgcn_cvt_pkrtz(Qc[2], Qc[3]);
    V8U fQ;
    fQ.u[0] = __builtin_amdgcn_ds_bpermute(idxA, (int)u0.u);
    fQ.u[1] = __builtin_amdgcn_ds_bpermute(idxA, (int)u1.u);
    fQ.u[2] = __builtin_amdgcn_ds_bpermute(idxB, (int)u0.u);
    fQ.u[3] = __builtin_amdgcn_ds_bpermute(idxB, (int)u1.u);
    v4f c5 = __builtin_amdgcn_mfma_f32_16x16x32_f16(Apk[j].v, fQ.v, z4, 0, 0, 0);
    E[j] = Cc + c5 * 0.5f;
  }

  // ---- squarings: E <- E*E (A-side exact hi/lo via LDS row transpose) ----
  int smax = max(max(sv[0], sv[1]), max(sv[2], sv[3]));
  for (int it = 0; it < smax; ++it) {
    #pragma unroll
    for (int j = 0; j < 4; ++j) {
      if (it < sv[j]) {
        float* Erp = ErW + j * 320;
        PkU u0, u1;
        u0.h = __builtin_amdgcn_cvt_pkrtz(E[j][0], E[j][1]);
        u1.h = __builtin_amdgcn_cvt_pkrtz(E[j][2], E[j][3]);
        V8U bfe;
        bfe.u[0] = __builtin_amdgcn_ds_bpermute(idxA, (int)u0.u);
        bfe.u[1] = __builtin_amdgcn_ds_bpermute(idxA, (int)u1.u);
        bfe.u[2] = __builtin_amdgcn_ds_bpermute(idxB, (int)u0.u);
        bfe.u[3] = __builtin_amdgcn_ds_bpermute(idxB, (int)u1.u);
        #pragma unroll
        for (int reg = 0; reg < 4; ++reg)
          Erp[(4 * q + reg) * 20 + nn] = E[j][reg];
        asm volatile("s_waitcnt lgkmcnt(0)" ::: "memory");
        float4 a0 = *(const float4*)(Erp + nn * 20 + b8);
        float4 a1 = *(const float4*)(Erp + nn * 20 + b8 + 4);
        float xa[8] = {a0.x, a0.y, a0.z, a0.w, a1.x, a1.y, a1.z, a1.w};
        v8h ahi, alo;
        split8(xa, ahi, alo);
        v8h Ecat = (q < 2) ? ahi : alo;
        v4f z = {0.f, 0.f, 0.f, 0.f};
        E[j] = __builtin_amdgcn_mfma_f32_16x16x32_f16(Ecat, bfe.v, z, 0, 0, 0);
      }
    }
  }

  // ---- store T + fused attn-weighted transported partials ----
  float pacc[4] = {0.f, 0.f, 0.f, 0.f};
  #pragma unroll
  for (int j = 0; j < 4; ++j) {
    int p = pbase + j;
    float* dst = Tg + (size_t)p * 256;
    #pragma unroll
    for (int reg = 0; reg < 4; ++reg)
      dst[(4 * q + reg) * 16 + nn] = E[j][reg];
    int b = p >> 14, i = p & 127;
    float xv = xm[((b << 7) + i) * 16 + nn];
    float aw = attn[(size_t)p] * xv;
    #pragma unroll
    for (int reg = 0; reg < 4; ++reg)
      pacc[reg] = fmaf(aw, E[j][reg], pacc[reg]);
  }
  #pragma unroll
  for (int reg = 0; reg < 4; ++reg) {
    #pragma unroll
    for (int off = 1; off < 16; off <<= 1)
      pacc[reg] += __shfl_xor(pacc[reg], off, 64);
  }
  if (nn == 0) {
    #pragma unroll
    for (int reg = 0; reg < 4; ++reg) sred[wu][4 * q + reg] = pacc[reg];
  }
  __syncthreads();
  if (t < 16)
    part[(size_t)blockIdx.x * 16 + t] =
        sred[0][t] + sred[1][t] + sred[2][t] + sred[3][t];
}

// ---------------------------------------------------------------------------
// K5: settled[bj] = sum of 8 per-block partials; out = settled @ Wo^T + bo
// ---------------------------------------------------------------------------
__global__ __launch_bounds__(64) void settle_fin_kernel(
    const float* __restrict__ part, const float* __restrict__ Wo,
    const float* __restrict__ bo, float* __restrict__ outp) {
  int bj = blockIdx.x, t = threadIdx.x;
  int r = t & 15, e0 = t >> 4;
  const float* pb = part + (size_t)bj * 128;  // 8 partials of 16
  float s = pb[e0 * 16 + r] + pb[(e0 + 4) * 16 + r];
  __shared__ float sf[64];
  sf[t] = s;
  __syncthreads();
  if (t < 16) sf[t] = sf[t] + sf[16 + t] + sf[32 + t] + sf[48 + t];
  __syncthreads();
  if (t < 16) {
    float o = bo[t];
    const float* wr = Wo + t * 16;
    #pragma unroll
    for (int c = 0; c < 16; ++c) o = fmaf(wr[c], sf[c], o);
    outp[bj * 16 + t] = o;
  }
}

// ---------------------------------------------------------------------------
extern "C" void kernel_launch(void* const* d_in, const int* in_sizes, int n_in,
                              void* d_out, int out_size, void* d_ws,
                              size_t ws_size, hipStream_t stream) {
  const float* xl = (const float*)d_in[0];
  const float* xm = (const float*)d_in[1];
  const float* Wq = (const float*)d_in[2];
  const float* bq = (const float*)d_in[3];
  const float* Wk = (const float*)d_in[4];
  const float* bk = (const float*)d_in[5];
  const float* W1 = (const float*)d_in[6];
  const float* b1 = (const float*)d_in[7];
  const float* W2 = (const float*)d_in[8];
  const float* b2 = (const float*)d_in[9];
  const float* Wo = (const float*)d_in[10];
  const float* bo = (const float*)d_in[11];
  float* outp = (float*)d_out;
  float* Tg = outp + 8192;  // [65536][256]: W2h f16 units [0,256) of slots
                            // 0..119 (disp1->disp3), skew A f16 units
                            // [256,512) (disp3->disp4), then T fp32.
  float* wsf = (float*)d_ws;
  float* Q = wsf;                // 65536
  float* K = wsf + 65536;        // 65536
  float* attn = wsf + 131072;    // 65536
  // u / part alias (stream-serial): u written disp 1, last read disp 3;
  // part first written disp 4.  Footprint stays at the validated 1.25 MB.
  float* u = wsf + 196608;       // 131072
  float* part = wsf + 196608;    // 4096*16 = 65536

  hipLaunchKernelGGL(qku_kernel, dim3(527), dim3(512), 0, stream, xl, Wq, bq, Wk, bk, W1, W2, Q, K, u, Tg);
  hipLaunchKernelGGL(attn_kernel, dim3(256), dim3(256), 0, stream, Q, K, attn);
  hipLaunchKernelGGL(lie_kernel, dim3(512), dim3(512), 0, stream, b2, u, b1, Tg);
  hipLaunchKernelGGL(expm_kernel, dim3(4096), dim3(256), 0, stream, Tg, attn, xm, part);
  hipLaunchKernelGGL(settle_fin_kernel, dim3(512), dim3(64), 0, stream, part, Wo, bo, outp);
}

// Round 12
// 182.483 us; speedup vs baseline: 1.0418x; 1.0283x over previous
//
#include <hip/hip_runtime.h>
#include <hip/hip_fp16.h>

// Problem constants
#define S_LEN 128
#define DLOG  128
#define DMEM  16
#define SO    120
#define HDIM  256

typedef _Float16 v8h __attribute__((ext_vector_type(8)));
typedef __fp16 v2hf __attribute__((ext_vector_type(2)));
typedef float v4f __attribute__((ext_vector_type(4)));

union PkU { v2hf h; unsigned u; };
union V8U { v8h v; int u[4]; };

__device__ __forceinline__ v8h splat8(float x) {
  _Float16 h = (_Float16)x;
  v8h v = {h, h, h, h, h, h, h, h};
  return v;
}

// ---------------------------------------------------------------------------
// K1: Q = x@Wq^T + bq,  K = x@Wk^T + bk,  u = x@W1^T
// Half-wave per output row, float4 weight reads, shfl tree reduce.
// Blocks >= 512 (15 of them) do the one-time W2 f32->f16 conversion into the
// dead h sub-windows of Tg (slot s, f16 units [0,256)).
// ---------------------------------------------------------------------------
__global__ __launch_bounds__(512) void qku_kernel(
    const float* __restrict__ xl, const float* __restrict__ Wq,
    const float* __restrict__ bq, const float* __restrict__ Wk,
    const float* __restrict__ bk, const float* __restrict__ W1,
    const float* __restrict__ W2g, float* __restrict__ Q,
    float* __restrict__ K, float* __restrict__ u, float* __restrict__ Tg) {
  int bj = blockIdx.x, t = threadIdx.x;
  if (bj >= 512) {
    int idx = (bj - 512) * 2048 + t * 4;  // 15*2048 = 30720 = 120*256
    float4 v = *(const float4*)(W2g + idx);
    PkU a, b;
    a.h = __builtin_amdgcn_cvt_pkrtz(v.x, v.y);
    b.h = __builtin_amdgcn_cvt_pkrtz(v.z, v.w);
    uint2 pk = {a.u, b.u};
    _Float16* w2hT = (_Float16*)Tg;
    *(uint2*)(w2hT + (idx >> 8) * 512 + (idx & 255)) = pk;
    return;
  }
  int lane = t & 63, wu = t >> 6;
  int half = lane >> 5, l5 = lane & 31;
  float4 xv = *(const float4*)(xl + bj * 128 + 4 * l5);
  int seg = wu >> 1;  // 0:Q(waves0-1) 1:K(waves2-3) >=2:u(waves4-7)
  const float* wb;
  if (seg == 0) wb = Wq;
  else if (seg == 1) wb = Wk - 128 * 128;
  else wb = W1 - 256 * 128;
  #pragma unroll 4
  for (int step = 0; step < 32; ++step) {
    int ro = wu * 64 + 2 * step + half;
    float4 wv = *(const float4*)(wb + ro * 128 + 4 * l5);
    float v = fmaf(wv.x, xv.x, fmaf(wv.y, xv.y, fmaf(wv.z, xv.z, wv.w * xv.w)));
    v += __shfl_xor(v, 1, 64);
    v += __shfl_xor(v, 2, 64);
    v += __shfl_xor(v, 4, 64);
    v += __shfl_xor(v, 8, 64);
    v += __shfl_xor(v, 16, 64);
    if (l5 == 0) {
      if (seg == 0) Q[bj * 128 + ro] = v + bq[ro];
      else if (seg == 1) K[bj * 128 + (ro - 128)] = v + bk[ro - 128];
      else u[bj * 256 + (ro - 256)] = v;
    }
  }
}

// ---------------------------------------------------------------------------
// K2 (merged lie + attn, one launch):
//  blocks [0,512):   fused h+lie, register-resident h.  One bj per block,
//    128 pairs, 8 waves.  A-frags computed in-register from u:
//    h[i][k] = tanh((u[bj][k]+b1[k]) - u[b,i][k]).  W2 staged per K-half
//    from the pre-converted f16 copy (pure 16B copies).  Epilogue builds the
//    full 16x16 f16 skew A per pair in LDS, writes coalesced to slot f16
//    units [256,512).
//  blocks [512,640): attn softmax, 4 bj per block (512 thr).  Independent of
//    the lie range (both read only disp-1 outputs) -> fills CUs during lie's
//    ramp-down, saves one launch gap.
// ---------------------------------------------------------------------------
__global__ __launch_bounds__(512) void lie_attn_kernel(
    const float* __restrict__ b2g, const float* __restrict__ ug,
    const float* __restrict__ b1g, float* __restrict__ Tg,
    const float* __restrict__ Q, const float* __restrict__ K,
    float* __restrict__ attn) {
  __shared__ _Float16 w2t[128 * 136];  // 34816 f16; reused as A-stage (16384)
  __shared__ float ujb[256];           // u[bj] + b1
  __shared__ float asc[4][128];        // attn-branch score rows
  __shared__ float ared[4][128];       // attn-branch reductions
  int t = threadIdx.x, lane = t & 63;

  if (blockIdx.x >= 512) {
    // ---- attn branch: 4 bj per block ----
    int sub = t >> 7, t128 = t & 127;
    int bj = (blockIdx.x - 512) * 4 + sub, b = bj >> 7;
    int wv_ = (t >> 6) & 1;
    int half = lane >> 5, l5 = lane & 31;
    float4 qv = *(const float4*)(Q + bj * 128 + 4 * l5);
    #pragma unroll 4
    for (int step = 0; step < 32; ++step) {
      int ro = wv_ * 64 + 2 * step + half;
      float4 kv = *(const float4*)(K + (size_t)(b * 128 + ro) * 128 + 4 * l5);
      float v = fmaf(kv.x, qv.x, fmaf(kv.y, qv.y, fmaf(kv.z, qv.z, kv.w * qv.w)));
      v += __shfl_xor(v, 1, 64);
      v += __shfl_xor(v, 2, 64);
      v += __shfl_xor(v, 4, 64);
      v += __shfl_xor(v, 8, 64);
      v += __shfl_xor(v, 16, 64);
      if (l5 == 0) asc[sub][ro] = v * 0.08838834764831845f;  // 1/sqrt(128)
    }
    __syncthreads();
    int i = t128;
    float s = asc[sub][i];
    ared[sub][i] = s;
    __syncthreads();
    for (int off = 64; off; off >>= 1) {
      if (i < off) ared[sub][i] = fmaxf(ared[sub][i], ared[sub][i + off]);
      __syncthreads();
    }
    float m = ared[sub][0];
    __syncthreads();
    float e = expf(s - m);
    ared[sub][i] = e;
    __syncthreads();
    for (int off = 64; off; off >>= 1) {
      if (i < off) ared[sub][i] += ared[sub][i + off];
      __syncthreads();
    }
    attn[(size_t)bj * 128 + i] = e / ared[sub][0];
    return;
  }

  // ---- lie branch ----
  int wu = __builtin_amdgcn_readfirstlane(t >> 6);
  int bj = blockIdx.x;  // one bj per block
  int b = bj >> 7;
  int nn = lane & 15, q = lane >> 4;
  int irow = wu * 16 + nn;  // pair's i index (0..127)
  const _Float16* w2hT = (const _Float16*)Tg;

  if (t < 256) ujb[t] = ug[bj * 256 + t] + b1g[t];
  // zero pad rows 120..127 once (never overwritten by staging)
  for (int idx = t; idx < 1088; idx += 512) w2t[16320 + idx] = (_Float16)0.f;

  v4f acc[8];
  #pragma unroll
  for (int tt = 0; tt < 8; ++tt) acc[tt] = (v4f){0.f, 0.f, 0.f, 0.f};

  const float* uib = ug + (size_t)(b * 128 + irow) * 256;

  for (int khalf = 0; khalf < 2; ++khalf) {
    __syncthreads();
    // stage W2 K-half: 120 rows x 128 cols f16 = 1920 v8h pure copies
    for (int idx = t; idx < 1920; idx += 512) {
      int row = idx >> 4, cu = (idx & 15) * 8;
      *(v8h*)(w2t + row * 136 + cu) =
          *(const v8h*)(w2hT + row * 512 + khalf * 128 + cu);
    }
    __syncthreads();
    #pragma unroll
    for (int ks = 0; ks < 4; ++ks) {
      int k0 = khalf * 128 + ks * 32 + 8 * q;
      float4 ui0 = *(const float4*)(uib + k0);
      float4 ui1 = *(const float4*)(uib + k0 + 4);
      float4 uj0 = *(const float4*)(ujb + k0);
      float4 uj1 = *(const float4*)(ujb + k0 + 4);
      float xv[8] = {uj0.x - ui0.x, uj0.y - ui0.y, uj0.z - ui0.z,
                     uj0.w - ui0.w, uj1.x - ui1.x, uj1.y - ui1.y,
                     uj1.z - ui1.z, uj1.w - ui1.w};
      float rv[8];
      #pragma unroll
      for (int k = 0; k < 8; ++k) {
        float x = xv[k];
        float ax = fabsf(x);
        float e = __expf(-2.f * ax);
        float r = __fdividef(1.f - e, 1.f + e);
        rv[k] = copysignf(r, x);
      }
      V8U ah;
      #pragma unroll
      for (int k = 0; k < 4; ++k) {
        PkU pu;
        pu.h = __builtin_amdgcn_cvt_pkrtz(rv[2 * k], rv[2 * k + 1]);
        ah.u[k] = (int)pu.u;
      }
      #pragma unroll
      for (int tt = 0; tt < 8; ++tt) {
        const v8h bf = *(const v8h*)(w2t + (16 * tt + nn) * 136 + ks * 32 + 8 * q);
        acc[tt] = __builtin_amdgcn_mfma_f32_16x16x32_f16(ah.v, bf, acc[tt], 0, 0, 0);
      }
    }
  }

  // precompute per-tt (r,c) positions and bias
  int rc0[8], rc1[8];
  float bbv[8];
  bool val[8];
  #pragma unroll
  for (int tt = 0; tt < 8; ++tt) {
    int n16 = 16 * tt + nn;
    val[tt] = (n16 < 120);
    // closed-form inverse of triangular index: r = floor((31-sqrt(961-8n))/2)
    float fr_ = floorf((31.0f - sqrtf(961.0f - 8.0f * (float)n16)) * 0.5f);
    int r = (int)fr_;
    int Sr = 15 * r - ((r * (r - 1)) >> 1);
    int c = n16 - Sr + r + 1;
    rc0[tt] = r * 16 + c;
    rc1[tt] = c * 16 + r;
    bbv[tt] = val[tt] ? b2g[n16] : 0.f;
  }

  _Float16* hw = (_Float16*)Tg;
  _Float16* aSt = w2t;  // [64 local pairs][256] f16 = 16384 f16 per pass
  for (int pass = 0; pass < 2; ++pass) {
    __syncthreads();
    // scatter phase: lanes owning pairs in this pass write A to LDS
    #pragma unroll
    for (int reg = 0; reg < 4; ++reg) {
      int pidx = 4 * q + reg;
      if ((pidx >> 3) == pass) {
        _Float16* ab = aSt + (wu * 8 + (pidx & 7)) * 256;
        #pragma unroll
        for (int tt = 0; tt < 8; ++tt) {
          if (val[tt]) {
            _Float16 hv = (_Float16)(acc[tt][reg] + bbv[tt]);
            ab[rc0[tt]] = hv;
            ab[rc1[tt]] = -hv;
          }
        }
        ab[nn * 17] = (_Float16)0.f;  // diag (each nn-lane writes one)
      }
    }
    __syncthreads();
    // copy phase: 2048 v8h units, fully coalesced
    #pragma unroll
    for (int k = 0; k < 4; ++k) {
      int unit = t + k * 512;
      int lp = unit >> 5, off = (unit & 31) * 8;
      int g = bj * 128 + (lp >> 3) * 16 + pass * 8 + (lp & 7);
      *(v8h*)(hw + (size_t)g * 512 + 256 + off) = *(const v8h*)(aSt + lp * 256 + off);
    }
  }
}

// ---------------------------------------------------------------------------
// K3: per-pair T = expm(skew(lie)) via Paterson-Stockmeyer even/odd split:
//   exp(A) = C(B) + A*Q(B),  B = A^2 (SYMMETRIC -> one bpermute transform
//   serves as BOTH MFMA operands).  4 pairs per wave (4 independent chains).
// Scaling: MFMA1 runs on UNSCALED f16 A (exact inputs, f32 accum); then
// theta^2 <= ||B||_inf; s from exponent bits; cB/Apk/Af scaled by exact
// powers of two afterwards.
// Epilogue computes attn-weighted transported partials (per-block) to `part`.
// ---------------------------------------------------------------------------
__device__ __forceinline__ void split8(const float* x, v8h& hi, v8h& lo) {
  union U { v8h v; v2hf p[4]; } H, L;
  #pragma unroll
  for (int i = 0; i < 4; ++i) {
    float a = x[2 * i], b = x[2 * i + 1];
    v2hf h = __builtin_amdgcn_cvt_pkrtz(a, b);
    float ra = (float)h[0], rb = (float)h[1];
    v2hf l = __builtin_amdgcn_cvt_pkrtz(a - ra, b - rb);
    H.p[i] = h;
    L.p[i] = l;
  }
  hi = H.v;
  lo = L.v;
}

__global__ __launch_bounds__(256) void expm_kernel(
    float* __restrict__ Tg, const float* __restrict__ attn,
    const float* __restrict__ xm, float* __restrict__ part) {
  __shared__ float ErB_all[4][1280];  // per-wave [4 pairs][320] f32
  __shared__ float sred[4][16];
  int t = threadIdx.x, lane = t & 63;
  int wu = __builtin_amdgcn_readfirstlane(t >> 6);
  int pbase = blockIdx.x * 16 + wu * 4;
  int nn = lane & 15, q = lane >> 4, b8 = (q & 1) * 8;
  float* ErW = ErB_all[wu];
  const _Float16* hf = (const _Float16*)Tg;

  int idxA = ((2 * (q & 1)) * 16 + nn) * 4;
  int idxB = idxA + 64;

  // ---- load A rows (full skew f16) UNSCALED ----
  V8U Apk[4];
  v4f Af[4];
  #pragma unroll
  for (int j = 0; j < 4; ++j) {
    size_t p = (size_t)(pbase + j);
    const _Float16* Ap = hf + p * 512 + 256;
    v8h rowh = *(const v8h*)(Ap + nn * 16 + b8);
    V8U ap;
    ap.v = rowh;
    #pragma unroll
    for (int i = 0; i < 4; ++i) Apk[j].u[i] = ap.u[i];
    #pragma unroll
    for (int reg = 0; reg < 4; ++reg)
      Af[j][reg] = (float)Ap[(4 * q + reg) * 16 + nn];
  }

  v4f z4 = {0.f, 0.f, 0.f, 0.f};

  // ---- MFMA1 (unscaled): cB_u = 2*A^2 ----
  v4f cB[4];
  #pragma unroll
  for (int j = 0; j < 4; ++j) {
    V8U bfa;
    #pragma unroll
    for (int i = 0; i < 4; ++i) bfa.u[i] = Apk[j].u[i] ^ 0x80008000;
    cB[j] = __builtin_amdgcn_mfma_f32_16x16x32_f16(Apk[j].v, bfa.v, z4, 0, 0, 0);
  }

  // ---- bound from ||B||_inf (col sums of symmetric B), scale exact pow2 ----
  int sv[4];
  #pragma unroll
  for (int j = 0; j < 4; ++j) {
    float cs = fabsf(cB[j][0]) + fabsf(cB[j][1]) + fabsf(cB[j][2]) +
               fabsf(cB[j][3]);
    cs += __shfl_xor(cs, 16, 64);   // sum over q (4 rows-of-4 per column)
    cs += __shfl_xor(cs, 32, 64);
    cs = fmaxf(cs, __shfl_xor(cs, 1, 64));   // max over columns nn
    cs = fmaxf(cs, __shfl_xor(cs, 2, 64));
    cs = fmaxf(cs, __shfl_xor(cs, 4, 64));
    cs = fmaxf(cs, __shfl_xor(cs, 8, 64));
    // cs = ||2B||_inf -> theta^2 <= ||B||_inf = cs/2
    float x = cs * 0.5f;
    int e = ((__float_as_int(x) >> 23) & 255) - 127;  // floor(log2 x)
    int s = min(12, max(0, (e + 2) >> 1));            // >= ceil(0.5*log2 x)
    sv[j] = __builtin_amdgcn_readfirstlane(s);
    float sc = __int_as_float((127 - sv[j]) << 23);   // 2^-s
    float sc2 = sc * sc;                              // 2^-2s
    cB[j] = cB[j] * sc2;
    Apk[j].v = Apk[j].v * splat8(sc);                 // exact pow2 in f16
    Af[j] = Af[j] * sc;
  }

  // identity frags in gather layout, pre-scaled by combo coefficients
  V8U IC1, IC2;
  #pragma unroll
  for (int i = 0; i < 4; ++i) {
    float d0 = (b8 + 2 * i == nn) ? 1.f : 0.f;
    float d1 = (b8 + 2 * i + 1 == nn) ? 1.f : 0.f;
    PkU u1, u2;
    u1.h = __builtin_amdgcn_cvt_pkrtz(10.666667f * d0, 10.666667f * d1);   // 256/24
    u2.h = __builtin_amdgcn_cvt_pkrtz(2.1333333f * d0, 2.1333333f * d1);   // 256/120
    IC1.u[i] = (int)u1.u;
    IC2.u[i] = (int)u2.u;
  }
  v8h k1a = splat8(7.9365079e-4f);   // 32/40320
  v8h k1b = splat8(0.17777778f);     // 128/720
  v8h k2a = splat8(8.8183422e-5f);   // 32/362880
  v8h k2b = splat8(2.5396825e-2f);   // 128/5040

  // ---- transform 1: fB = gather(2B) ----
  V8U fB[4];
  #pragma unroll
  for (int j = 0; j < 4; ++j) {
    PkU u0, u1;
    u0.h = __builtin_amdgcn_cvt_pkrtz(cB[j][0], cB[j][1]);
    u1.h = __builtin_amdgcn_cvt_pkrtz(cB[j][2], cB[j][3]);
    fB[j].u[0] = __builtin_amdgcn_ds_bpermute(idxA, (int)u0.u);
    fB[j].u[1] = __builtin_amdgcn_ds_bpermute(idxA, (int)u1.u);
    fB[j].u[2] = __builtin_amdgcn_ds_bpermute(idxB, (int)u0.u);
    fB[j].u[3] = __builtin_amdgcn_ds_bpermute(idxB, (int)u1.u);
  }

  // ---- MFMA2 + transform 2: fB2 = gather(8*B^2) ----
  V8U fB2[4];
  #pragma unroll
  for (int j = 0; j < 4; ++j) {
    v4f c = __builtin_amdgcn_mfma_f32_16x16x32_f16(fB[j].v, fB[j].v, z4, 0, 0, 0);
    PkU u0, u1;
    u0.h = __builtin_amdgcn_cvt_pkrtz(c[0], c[1]);
    u1.h = __builtin_amdgcn_cvt_pkrtz(c[2], c[3]);
    fB2[j].u[0] = __builtin_amdgcn_ds_bpermute(idxA, (int)u0.u);
    fB2[j].u[1] = __builtin_amdgcn_ds_bpermute(idxA, (int)u1.u);
    fB2[j].u[2] = __builtin_amdgcn_ds_bpermute(idxB, (int)u0.u);
    fB2[j].u[3] = __builtin_amdgcn_ds_bpermute(idxB, (int)u1.u);
  }

  // ---- fused tail: combos -> MFMA3/4 -> fQ gather -> MFMA5 -> E ----
  v4f E[4];
  #pragma unroll
  for (int j = 0; j < 4; ++j) {
    V8U M1, M2;
    M1.v = fB2[j].v * k1a + (fB[j].v * k1b + IC1.v);
    M2.v = fB2[j].v * k2a + (fB[j].v * k2b + IC2.v);
    v4f c3m = __builtin_amdgcn_mfma_f32_16x16x32_f16(M1.v, fB2[j].v, z4, 0, 0, 0);
    v4f c4m = __builtin_amdgcn_mfma_f32_16x16x32_f16(M2.v, fB2[j].v, z4, 0, 0, 0);
    v4f Cc, Qc;
    #pragma unroll
    for (int reg = 0; reg < 4; ++reg) {
      float dg = (4 * q + reg == nn) ? 1.f : 0.f;
      Cc[reg] = fmaf(c3m[reg], 2.44140625e-4f,
                     fmaf(cB[j][reg], 0.25f, dg + Af[j][reg]));
      Qc[reg] = fmaf(c4m[reg], 2.44140625e-4f, cB[j][reg] * 0.083333333f);
    }
    PkU u0, u1;
    u0.h = __builtin_amdgcn_cvt_pkrtz(Qc[0], Qc[1]);
    u1.h = __builtin_amdgcn_cvt_pkrtz(Qc[2], Qc[3]);
    V8U fQ;
    fQ.u[0] = __builtin_amdgcn_ds_bpermute(idxA, (int)u0.u);
    fQ.u[1] = __builtin_amdgcn_ds_bpermute(idxA, (int)u1.u);
    fQ.u[2] = __builtin_amdgcn_ds_bpermute(idxB, (int)u0.u);
    fQ.u[3] = __builtin_amdgcn_ds_bpermute(idxB, (int)u1.u);
    v4f c5 = __builtin_amdgcn_mfma_f32_16x16x32_f16(Apk[j].v, fQ.v, z4, 0, 0, 0);
    E[j] = Cc + c5 * 0.5f;
  }

  // ---- squarings: E <- E*E (A-side exact hi/lo via LDS row transpose) ----
  int smax = max(max(sv[0], sv[1]), max(sv[2], sv[3]));
  for (int it = 0; it < smax; ++it) {
    #pragma unroll
    for (int j = 0; j < 4; ++j) {
      if (it < sv[j]) {
        float* Erp = ErW + j * 320;
        PkU u0, u1;
        u0.h = __builtin_amdgcn_cvt_pkrtz(E[j][0], E[j][1]);
        u1.h = __builtin_amdgcn_cvt_pkrtz(E[j][2], E[j][3]);
        V8U bfe;
        bfe.u[0] = __builtin_amdgcn_ds_bpermute(idxA, (int)u0.u);
        bfe.u[1] = __builtin_amdgcn_ds_bpermute(idxA, (int)u1.u);
        bfe.u[2] = __builtin_amdgcn_ds_bpermute(idxB, (int)u0.u);
        bfe.u[3] = __builtin_amdgcn_ds_bpermute(idxB, (int)u1.u);
        #pragma unroll
        for (int reg = 0; reg < 4; ++reg)
          Erp[(4 * q + reg) * 20 + nn] = E[j][reg];
        asm volatile("s_waitcnt lgkmcnt(0)" ::: "memory");
        float4 a0 = *(const float4*)(Erp + nn * 20 + b8);
        float4 a1 = *(const float4*)(Erp + nn * 20 + b8 + 4);
        float xa[8] = {a0.x, a0.y, a0.z, a0.w, a1.x, a1.y, a1.z, a1.w};
        v8h ahi, alo;
        split8(xa, ahi, alo);
        v8h Ecat = (q < 2) ? ahi : alo;
        v4f z = {0.f, 0.f, 0.f, 0.f};
        E[j] = __builtin_amdgcn_mfma_f32_16x16x32_f16(Ecat, bfe.v, z, 0, 0, 0);
      }
    }
  }

  // ---- store T + fused attn-weighted transported partials ----
  float pacc[4] = {0.f, 0.f, 0.f, 0.f};
  #pragma unroll
  for (int j = 0; j < 4; ++j) {
    int p = pbase + j;
    float* dst = Tg + (size_t)p * 256;
    #pragma unroll
    for (int reg = 0; reg < 4; ++reg)
      dst[(4 * q + reg) * 16 + nn] = E[j][reg];
    int b = p >> 14, i = p & 127;
    float xv = xm[((b << 7) + i) * 16 + nn];
    float aw = attn[(size_t)p] * xv;
    #pragma unroll
    for (int reg = 0; reg < 4; ++reg)
      pacc[reg] = fmaf(aw, E[j][reg], pacc[reg]);
  }
  #pragma unroll
  for (int reg = 0; reg < 4; ++reg) {
    #pragma unroll
    for (int off = 1; off < 16; off <<= 1)
      pacc[reg] += __shfl_xor(pacc[reg], off, 64);
  }
  if (nn == 0) {
    #pragma unroll
    for (int reg = 0; reg < 4; ++reg) sred[wu][4 * q + reg] = pacc[reg];
  }
  __syncthreads();
  if (t < 16)
    part[(size_t)blockIdx.x * 16 + t] =
        sred[0][t] + sred[1][t] + sred[2][t] + sred[3][t];
}

// ---------------------------------------------------------------------------
// K4: settled[bj] = sum of 8 per-block partials; out = settled @ Wo^T + bo
// ---------------------------------------------------------------------------
__global__ __launch_bounds__(64) void settle_fin_kernel(
    const float* __restrict__ part, const float* __restrict__ Wo,
    const float* __restrict__ bo, float* __restrict__ outp) {
  int bj = blockIdx.x, t = threadIdx.x;
  int r = t & 15, e0 = t >> 4;
  const float* pb = part + (size_t)bj * 128;  // 8 partials of 16
  float s = pb[e0 * 16 + r] + pb[(e0 + 4) * 16 + r];
  __shared__ float sf[64];
  sf[t] = s;
  __syncthreads();
  if (t < 16) sf[t] = sf[t] + sf[16 + t] + sf[32 + t] + sf[48 + t];
  __syncthreads();
  if (t < 16) {
    float o = bo[t];
    const float* wr = Wo + t * 16;
    #pragma unroll
    for (int c = 0; c < 16; ++c) o = fmaf(wr[c], sf[c], o);
    outp[bj * 16 + t] = o;
  }
}

// ---------------------------------------------------------------------------
extern "C" void kernel_launch(void* const* d_in, const int* in_sizes, int n_in,
                              void* d_out, int out_size, void* d_ws,
                              size_t ws_size, hipStream_t stream) {
  const float* xl = (const float*)d_in[0];
  const float* xm = (const float*)d_in[1];
  const float* Wq = (const float*)d_in[2];
  const float* bq = (const float*)d_in[3];
  const float* Wk = (const float*)d_in[4];
  const float* bk = (const float*)d_in[5];
  const float* W1 = (const float*)d_in[6];
  const float* b1 = (const float*)d_in[7];
  const float* W2 = (const float*)d_in[8];
  const float* b2 = (const float*)d_in[9];
  const float* Wo = (const float*)d_in[10];
  const float* bo = (const float*)d_in[11];
  float* outp = (float*)d_out;
  float* Tg = outp + 8192;  // [65536][256]: W2h f16 units [0,256) of slots
                            // 0..119 (disp1->disp2), skew A f16 units
                            // [256,512) (disp2->disp3), then T fp32.
  float* wsf = (float*)d_ws;
  float* Q = wsf;                // 65536
  float* K = wsf + 65536;        // 65536
  float* attn = wsf + 131072;    // 65536
  // u / part alias (stream-serial): u written disp 1, last read disp 2;
  // part first written disp 3.  Footprint stays at the validated 1.25 MB.
  float* u = wsf + 196608;       // 131072
  float* part = wsf + 196608;    // 4096*16 = 65536

  hipLaunchKernelGGL(qku_kernel, dim3(527), dim3(512), 0, stream, xl, Wq, bq, Wk, bk, W1, W2, Q, K, u, Tg);
  hipLaunchKernelGGL(lie_attn_kernel, dim3(640), dim3(512), 0, stream, b2, u, b1, Tg, Q, K, attn);
  hipLaunchKernelGGL(expm_kernel, dim3(4096), dim3(256), 0, stream, Tg, attn, xm, part);
  hipLaunchKernelGGL(settle_fin_kernel, dim3(512), dim3(64), 0, stream, part, Wo, bo, outp);
}